// Round 5
// baseline (268.795 us; speedup 1.0000x reference)
//
#include <hip/hip_runtime.h>

// Problem constants (fixed by setup_inputs).
#define Bn   8
#define Cn   256
#define MIDn 16
#define Hn   128
#define Wn   128
#define HWn  (Hn * Wn)      // 16384

// ---------------------------------------------------------------------------
// KA: full 1x1 reduce (256 -> 16), intra-block channel split.
// Block covers 64 float2 pixels (128 px); wave w handles channels [64w,64w+64).
// LDS combine (4 waves -> 1) then single xlow write.
// Grid (128, 8) = 1024 blocks; ~27 us vs 22.6 us traffic floor -- near floor.
// ---------------------------------------------------------------------------
__global__ __launch_bounds__(256, 4) void reduce_k(const float2* __restrict__ x2,
                                                   const float* __restrict__ wr,
                                                   float2* __restrict__ xlow2) {
    __shared__ float2 comb[4][MIDn][64];    // 32768 B

    const int tid = threadIdx.x;
    const int p2  = tid & 63;               // float2 index within block's range
    const int wv  = tid >> 6;               // wave id = channel group
    const int b   = blockIdx.y;
    const int p0  = blockIdx.x * 64;

    // wave-uniform channel base -> SGPR, so weight reads become s_loads
    const int c0 = __builtin_amdgcn_readfirstlane(wv << 6);

    const float2* xb = x2 + ((size_t)b * Cn + c0) * (HWn / 2) + p0 + p2;

    float2 acc[MIDn];
#pragma unroll
    for (int m = 0; m < MIDn; ++m) acc[m] = make_float2(0.f, 0.f);

#pragma unroll 8
    for (int c = 0; c < 64; ++c) {
        const float2 v = xb[(size_t)c * (HWn / 2)];   // 512 B / wave, coalesced
        const float* w = wr + (c0 + c);               // lane-uniform -> s_load
#pragma unroll
        for (int m = 0; m < MIDn; ++m) {
            const float wm = w[m * Cn];
            acc[m].x = fmaf(v.x, wm, acc[m].x);
            acc[m].y = fmaf(v.y, wm, acc[m].y);
        }
    }

#pragma unroll
    for (int m = 0; m < MIDn; ++m) comb[wv][m][p2] = acc[m];
    __syncthreads();

    float2* ob = xlow2 + (size_t)b * MIDn * (HWn / 2) + p0;
#pragma unroll
    for (int k = 0; k < 4; ++k) {
        const int idx = k * 256 + tid;
        const int m   = idx >> 6;
        const int q   = idx & 63;
        const float2 s0 = comb[0][m][q];
        const float2 s1 = comb[1][m][q];
        const float2 s2 = comb[2][m][q];
        const float2 s3 = comb[3][m][q];
        float2 s;
        s.x = (s0.x + s1.x) + (s2.x + s3.x);
        s.y = (s0.y + s1.y) + (s2.y + s3.y);
        ob[(size_t)m * (HWn / 2) + q] = s;
    }
}

// ---------------------------------------------------------------------------
// KB v5: fused separable conv + expand, BARRIER-FREE tail.
// Round-4 null proved the grid (1024 blocks) is fully co-resident and runs
// in lockstep: stage burst -> compute (HBM idle) -> store burst. The fix is
// not more residency but DE-SYNCHRONIZATION: drop the low[] LDS exchange,
// have each thread compute all 16 mids for its own pixel (2 threads/px,
// redundant B2 -- cheap after separable factorization) and stream its 128
// expand channels directly from registers. No barrier after B1 writeback:
// waves drift apart, stores are paced 1-per-16-FMA across ~85% of the
// kernel, overlapping read/compute/write pipes.
// Phases: A stage | B1 vertical in-place (vu rows 0..3, vv rows 4..7)
//         | B2 per-px 16 mids -> regs | C 128-channel expand (no syncs).
// LDS 24.3 KB, 6 blocks/CU; barriers 5 -> 3.
// ---------------------------------------------------------------------------
#define TW 32
#define TH 4
#define HR (TH + 6)   // 10
#define WR (TW + 6)   // 38
#define NPX (TH * TW) // 128
#define NSTRIP (MIDn * WR)  // 608

__device__ __forceinline__ int reflect_i(int i, int n) {
    return i < 0 ? -i : (i >= n ? 2 * n - 2 - i : i);
}

__global__ __launch_bounds__(256, 6) void conv_expand_k(const float* __restrict__ xlow,
                                                        const float* __restrict__ ang,
                                                        const float* __restrict__ we,
                                                        float* __restrict__ out) {
    __shared__ float tile[MIDn][HR][WR];  // 24320 B (sole LDS use)

    const int tid = threadIdx.x;
    const int b   = blockIdx.y;
    const int rem = blockIdx.x;           // 0..127 -> 32 x 4 tiles
    const int th0 = (rem >> 2) * TH;
    const int tw0 = (rem & 3) * TW;

    // px ownership: threads tid and tid+128 share a px (redundant B2),
    // and split the 256 expand channels between them.
    const int px = tid & (NPX - 1);       // 0..127
    const int pr = px >> 5;
    const int pc = px & 31;

    // issue the angle load early (independent of LDS phases)
    const float a = ang[(size_t)b * HWn + (th0 + pr) * Wn + (tw0 + pc)];

    // basis taps (fu3 = fv3 = 1 exactly)
    const float fu0 = 0.48675226f, fu1 = 0.72614904f, fu2 = 0.92311635f;
    const float fv0 = 0.011108997f, fv1 = 0.13533528f, fv2 = 0.60653066f;

    // ---- Phase A: stage halo tile (reflect-indexed) for all 16 mids ----
    const float* pb = xlow + (size_t)b * MIDn * HWn;
    for (int idx = tid; idx < MIDn * HR * WR; idx += 256) {
        const int m  = idx / (HR * WR);
        const int r2 = idx - m * (HR * WR);
        const int r  = r2 / WR;
        const int cc = r2 - r * WR;
        const int gr = reflect_i(th0 + r - 3, Hn);
        const int gc = reflect_i(tw0 + cc - 3, Wn);
        tile[m][r][cc] = pb[(size_t)m * HWn + gr * Wn + gc];
    }
    __syncthreads();

    // ---- Phase B1: vertical pass, in-place. 608 column strips / 256 thr. ----
    float oA[8], oB[8], oC[8];
    int mA, cA, mB, cB, mC, cC;
    bool hasC;
    {
        {   // strip A: s = tid
            const int s = tid;
            mA = s / WR; cA = s - mA * WR;
            float t[HR];
#pragma unroll
            for (int r = 0; r < HR; ++r) t[r] = tile[mA][r][cA];
#pragma unroll
            for (int r = 0; r < TH; ++r) {
                const float p06 = t[r] + t[r + 6];
                const float p15 = t[r + 1] + t[r + 5];
                const float p24 = t[r + 2] + t[r + 4];
                const float p3  = t[r + 3];
                oA[r]     = fmaf(fu0, p06, fmaf(fu1, p15, fmaf(fu2, p24, p3)));
                oA[4 + r] = fmaf(fv0, p06, fmaf(fv1, p15, fmaf(fv2, p24, p3)));
            }
        }
        {   // strip B: s = tid + 256
            const int s = tid + 256;
            mB = s / WR; cB = s - mB * WR;
            float t[HR];
#pragma unroll
            for (int r = 0; r < HR; ++r) t[r] = tile[mB][r][cB];
#pragma unroll
            for (int r = 0; r < TH; ++r) {
                const float p06 = t[r] + t[r + 6];
                const float p15 = t[r + 1] + t[r + 5];
                const float p24 = t[r + 2] + t[r + 4];
                const float p3  = t[r + 3];
                oB[r]     = fmaf(fu0, p06, fmaf(fu1, p15, fmaf(fu2, p24, p3)));
                oB[4 + r] = fmaf(fv0, p06, fmaf(fv1, p15, fmaf(fv2, p24, p3)));
            }
        }
        // strip C: s = tid + 512 (only tid < 96)
        hasC = (tid + 512) < NSTRIP;
        {
            const int s = hasC ? (tid + 512) : tid;   // safe dummy when !hasC
            mC = s / WR; cC = s - mC * WR;
            float t[HR];
#pragma unroll
            for (int r = 0; r < HR; ++r) t[r] = tile[mC][r][cC];
#pragma unroll
            for (int r = 0; r < TH; ++r) {
                const float p06 = t[r] + t[r + 6];
                const float p15 = t[r + 1] + t[r + 5];
                const float p24 = t[r + 2] + t[r + 4];
                const float p3  = t[r + 3];
                oC[r]     = fmaf(fu0, p06, fmaf(fu1, p15, fmaf(fu2, p24, p3)));
                oC[4 + r] = fmaf(fv0, p06, fmaf(fv1, p15, fmaf(fv2, p24, p3)));
            }
        }
    }
    __syncthreads();   // all reads of tile complete before in-place writes

#pragma unroll
    for (int r = 0; r < TH; ++r) {
        tile[mA][r][cA]     = oA[r];
        tile[mA][4 + r][cA] = oA[4 + r];
        tile[mB][r][cB]     = oB[r];
        tile[mB][4 + r][cB] = oB[4 + r];
    }
    if (hasC) {
#pragma unroll
        for (int r = 0; r < TH; ++r) {
            tile[mC][r][cC]     = oC[r];
            tile[mC][4 + r][cC] = oC[4 + r];
        }
    }
    __syncthreads();
    // tile[m][0..3][*] = vu (fu-vertical), tile[m][4..7][*] = vv (fv-vertical).
    // NO MORE BARRIERS: B2 only reads tile; C doesn't touch LDS.

    // ---- Phase B2: horizontal 7-tap + blend, ALL 16 mids -> registers ----
    float lowr[MIDn];
    {
        const float ch = cosf(a);
        const float wh = ch * ch;
        const float su = 1.f + 2.f * (0.48675226f + 0.72614904f + 0.92311635f);
        const float sv = 1.f + 2.f * (0.011108997f + 0.13533528f + 0.60653066f);
        const float inv = 1.f / (su * sv + 1e-8f);    // matches ker.sum()+1e-8
        const float aH = wh * inv;
        const float aV = (1.f - wh) * inv;

#pragma unroll
        for (int m = 0; m < MIDn; ++m) {
            // SH: vertical fu (rows 0..3) then horizontal fv
            const float h06 = tile[m][pr][pc] + tile[m][pr][pc + 6];
            const float h15 = tile[m][pr][pc + 1] + tile[m][pr][pc + 5];
            const float h24 = tile[m][pr][pc + 2] + tile[m][pr][pc + 4];
            const float accH = fmaf(fv0, h06, fmaf(fv1, h15, fmaf(fv2, h24, tile[m][pr][pc + 3])));
            // SV: vertical fv (rows 4..7) then horizontal fu
            const float g06 = tile[m][4 + pr][pc] + tile[m][4 + pr][pc + 6];
            const float g15 = tile[m][4 + pr][pc + 1] + tile[m][4 + pr][pc + 5];
            const float g24 = tile[m][4 + pr][pc + 2] + tile[m][4 + pr][pc + 4];
            const float accV = fmaf(fu0, g06, fmaf(fu1, g15, fmaf(fu2, g24, tile[m][4 + pr][pc + 3])));
            lowr[m] = fmaf(aH, accH, aV * accV);
        }
    }

    // ---- Phase C: expand; this thread's px, channels [ch0, ch0+128) ----
    // Stores paced 1-per-16-FMA: 256 B/instr in 2x128 B segments, spread
    // across the kernel as waves de-synchronize.
    const int ch0 = __builtin_amdgcn_readfirstlane((tid >> 7) << 7);  // wave-uniform

    float* ob = out + ((size_t)b * Cn + ch0) * HWn + (th0 + pr) * Wn + (tw0 + pc);
#pragma unroll 4
    for (int ci = 0; ci < 128; ++ci) {
        const float* w = we + (size_t)(ch0 + ci) * MIDn;   // lane-uniform -> s_load
        float o = 0.f;
#pragma unroll
        for (int m = 0; m < MIDn; ++m) o = fmaf(w[m], lowr[m], o);
        ob[(size_t)ci * HWn] = o;
    }
}

// ---------------------------------------------------------------------------
extern "C" void kernel_launch(void* const* d_in, const int* in_sizes, int n_in,
                              void* d_out, int out_size, void* d_ws, size_t ws_size,
                              hipStream_t stream) {
    const float* x   = (const float*)d_in[0];  // (8,256,128,128)
    const float* ang = (const float*)d_in[1];  // (8,128,128)
    const float* wr  = (const float*)d_in[2];  // (16,256)
    const float* we  = (const float*)d_in[3];  // (256,16)
    float*       out = (float*)d_out;          // (8,256,128,128)

    float* xlow = (float*)d_ws;                // 8 MiB: (8,16,128,128)

    reduce_k<<<dim3((HWn / 2) / 64, Bn), dim3(256), 0, stream>>>(
        (const float2*)x, wr, (float2*)xlow);
    conv_expand_k<<<dim3(128, Bn), dim3(256), 0, stream>>>(xlow, ang, we, out);
}

// Round 6
// 266.322 us; speedup vs baseline: 1.0093x; 1.0093x over previous
//
#include <hip/hip_runtime.h>

// Problem constants (fixed by setup_inputs).
#define Bn   8
#define Cn   256
#define MIDn 16
#define Hn   128
#define Wn   128
#define HWn  (Hn * Wn)      // 16384

// ---------------------------------------------------------------------------
// KA: full 1x1 reduce (256 -> 16), intra-block channel split.
// Block covers 64 float2 pixels (128 px); wave w handles channels [64w,64w+64).
// LDS combine (4 waves -> 1) then single xlow write.
// Grid (128, 8) = 1024 blocks; ~27 us vs 22.6 us traffic floor -- near floor.
// ---------------------------------------------------------------------------
__global__ __launch_bounds__(256, 4) void reduce_k(const float2* __restrict__ x2,
                                                   const float* __restrict__ wr,
                                                   float2* __restrict__ xlow2) {
    __shared__ float2 comb[4][MIDn][64];    // 32768 B

    const int tid = threadIdx.x;
    const int p2  = tid & 63;               // float2 index within block's range
    const int wv  = tid >> 6;               // wave id = channel group
    const int b   = blockIdx.y;
    const int p0  = blockIdx.x * 64;

    // wave-uniform channel base -> SGPR, so weight reads become s_loads
    const int c0 = __builtin_amdgcn_readfirstlane(wv << 6);

    const float2* xb = x2 + ((size_t)b * Cn + c0) * (HWn / 2) + p0 + p2;

    float2 acc[MIDn];
#pragma unroll
    for (int m = 0; m < MIDn; ++m) acc[m] = make_float2(0.f, 0.f);

#pragma unroll 8
    for (int c = 0; c < 64; ++c) {
        const float2 v = xb[(size_t)c * (HWn / 2)];   // 512 B / wave, coalesced
        const float* w = wr + (c0 + c);               // lane-uniform -> s_load
#pragma unroll
        for (int m = 0; m < MIDn; ++m) {
            const float wm = w[m * Cn];
            acc[m].x = fmaf(v.x, wm, acc[m].x);
            acc[m].y = fmaf(v.y, wm, acc[m].y);
        }
    }

#pragma unroll
    for (int m = 0; m < MIDn; ++m) comb[wv][m][p2] = acc[m];
    __syncthreads();

    float2* ob = xlow2 + (size_t)b * MIDn * (HWn / 2) + p0;
#pragma unroll
    for (int k = 0; k < 4; ++k) {
        const int idx = k * 256 + tid;
        const int m   = idx >> 6;
        const int q   = idx & 63;
        const float2 s0 = comb[0][m][q];
        const float2 s1 = comb[1][m][q];
        const float2 s2 = comb[2][m][q];
        const float2 s3 = comb[3][m][q];
        float2 s;
        s.x = (s0.x + s1.x) + (s2.x + s3.x);
        s.y = (s0.y + s1.y) + (s2.y + s3.y);
        ob[(size_t)m * (HWn / 2) + q] = s;
    }
}

// ---------------------------------------------------------------------------
// KB v6: v4 structure + CHANNEL-SPLIT x2 for cross-block pipelining.
// R4 proved the 1024-block grid is fully co-resident (no block turnover);
// R5 proved intra-block de-sync doesn't work (stores must burst from many
// waves, not pace within one). So: 2 blocks per tile, each expanding 128
// of the 256 channels -> grid (128,2,8) = 2048 blocks at 6-deep residency.
// Blocks queue: a draining block's stores overlap the next block's stage
// reads on the same CU. Cost: A/B1/B2 run twice per tile (+~26 MB fetch,
// +~3 us chip VALU) -- small vs the phase-serialization removed.
// Phases: A stage | B1 vertical in-place | B2 horizontal+blend -> regs
//         | overlay low onto dead vu rows | C expand 128 ch, float2 stores.
// LDS 24.3 KB (6 blocks/CU), barriers 5.
// ---------------------------------------------------------------------------
#define TW 32
#define TH 4
#define HR (TH + 6)   // 10
#define WR (TW + 6)   // 38
#define NPX (TH * TW) // 128
#define NSTRIP (MIDn * WR)  // 608
#define MSTRIDE (HR * WR)   // 380 floats per mid in tile

__device__ __forceinline__ int reflect_i(int i, int n) {
    return i < 0 ? -i : (i >= n ? 2 * n - 2 - i : i);
}

__global__ __launch_bounds__(256, 6) void conv_expand_k(const float* __restrict__ xlow,
                                                        const float* __restrict__ ang,
                                                        const float* __restrict__ we,
                                                        float2* __restrict__ out2) {
    __shared__ float tile[MIDn][HR][WR];  // 24320 B (sole LDS use)
    float* tf = &tile[0][0][0];           // flat alias for the low overlay

    const int tid = threadIdx.x;
    const int b   = blockIdx.z;
    const int chh = blockIdx.y;           // channel half: 0 -> [0,128), 1 -> [128,256)
    const int rem = blockIdx.x;           // 0..127 -> 32 x 4 tiles
    const int th0 = (rem >> 2) * TH;
    const int tw0 = (rem & 3) * TW;

    // issue the angle load early (independent of LDS phases)
    const int px = tid & (NPX - 1);       // 0..127
    const int mh = tid >> 7;              // 0/1 (wave-uniform) -> mids [8*mh, 8*mh+8)
    const int pr = px >> 5;
    const int pc = px & 31;
    const float a = ang[(size_t)b * HWn + (th0 + pr) * Wn + (tw0 + pc)];

    // basis taps (fu3 = fv3 = 1 exactly)
    const float fu0 = 0.48675226f, fu1 = 0.72614904f, fu2 = 0.92311635f;
    const float fv0 = 0.011108997f, fv1 = 0.13533528f, fv2 = 0.60653066f;

    // ---- Phase A: stage halo tile (reflect-indexed) for all 16 mids ----
    const float* pb = xlow + (size_t)b * MIDn * HWn;
    for (int idx = tid; idx < MIDn * HR * WR; idx += 256) {
        const int m  = idx / (HR * WR);
        const int r2 = idx - m * (HR * WR);
        const int r  = r2 / WR;
        const int cc = r2 - r * WR;
        const int gr = reflect_i(th0 + r - 3, Hn);
        const int gc = reflect_i(tw0 + cc - 3, Wn);
        tile[m][r][cc] = pb[(size_t)m * HWn + gr * Wn + gc];
    }
    __syncthreads();

    // ---- Phase B1: vertical pass, in-place. 608 column strips / 256 thr. ----
    float oA[8], oB[8], oC[8];
    int mA, cA, mB, cB, mC, cC;
    bool hasC;
    {
        {   // strip A: s = tid
            const int s = tid;
            mA = s / WR; cA = s - mA * WR;
            float t[HR];
#pragma unroll
            for (int r = 0; r < HR; ++r) t[r] = tile[mA][r][cA];
#pragma unroll
            for (int r = 0; r < TH; ++r) {
                const float p06 = t[r] + t[r + 6];
                const float p15 = t[r + 1] + t[r + 5];
                const float p24 = t[r + 2] + t[r + 4];
                const float p3  = t[r + 3];
                oA[r]     = fmaf(fu0, p06, fmaf(fu1, p15, fmaf(fu2, p24, p3)));
                oA[4 + r] = fmaf(fv0, p06, fmaf(fv1, p15, fmaf(fv2, p24, p3)));
            }
        }
        {   // strip B: s = tid + 256
            const int s = tid + 256;
            mB = s / WR; cB = s - mB * WR;
            float t[HR];
#pragma unroll
            for (int r = 0; r < HR; ++r) t[r] = tile[mB][r][cB];
#pragma unroll
            for (int r = 0; r < TH; ++r) {
                const float p06 = t[r] + t[r + 6];
                const float p15 = t[r + 1] + t[r + 5];
                const float p24 = t[r + 2] + t[r + 4];
                const float p3  = t[r + 3];
                oB[r]     = fmaf(fu0, p06, fmaf(fu1, p15, fmaf(fu2, p24, p3)));
                oB[4 + r] = fmaf(fv0, p06, fmaf(fv1, p15, fmaf(fv2, p24, p3)));
            }
        }
        // strip C: s = tid + 512 (only tid < 96)
        hasC = (tid + 512) < NSTRIP;
        {
            const int s = hasC ? (tid + 512) : tid;   // safe dummy when !hasC
            mC = s / WR; cC = s - mC * WR;
            float t[HR];
#pragma unroll
            for (int r = 0; r < HR; ++r) t[r] = tile[mC][r][cC];
#pragma unroll
            for (int r = 0; r < TH; ++r) {
                const float p06 = t[r] + t[r + 6];
                const float p15 = t[r + 1] + t[r + 5];
                const float p24 = t[r + 2] + t[r + 4];
                const float p3  = t[r + 3];
                oC[r]     = fmaf(fu0, p06, fmaf(fu1, p15, fmaf(fu2, p24, p3)));
                oC[4 + r] = fmaf(fv0, p06, fmaf(fv1, p15, fmaf(fv2, p24, p3)));
            }
        }
    }
    __syncthreads();   // all reads of tile complete before in-place writes

#pragma unroll
    for (int r = 0; r < TH; ++r) {
        tile[mA][r][cA]     = oA[r];
        tile[mA][4 + r][cA] = oA[4 + r];
        tile[mB][r][cB]     = oB[r];
        tile[mB][4 + r][cB] = oB[4 + r];
    }
    if (hasC) {
#pragma unroll
        for (int r = 0; r < TH; ++r) {
            tile[mC][r][cC]     = oC[r];
            tile[mC][4 + r][cC] = oC[4 + r];
        }
    }
    __syncthreads();
    // now: tile[m][0..3][*] = vu (fu-vertical), tile[m][4..7][*] = vv (fv-vertical)

    // ---- Phase B2: horizontal 7-tap + blend -> registers (8 mids/thread) ----
    float lowr[8];
    {
        const float ch = cosf(a);
        const float wh = ch * ch;
        const float su = 1.f + 2.f * (0.48675226f + 0.72614904f + 0.92311635f);
        const float sv = 1.f + 2.f * (0.011108997f + 0.13533528f + 0.60653066f);
        const float inv = 1.f / (su * sv + 1e-8f);    // matches ker.sum()+1e-8
        const float aH = wh * inv;
        const float aV = (1.f - wh) * inv;

        const int m0 = mh * 8;
#pragma unroll
        for (int mm = 0; mm < 8; ++mm) {
            const int m = m0 + mm;
            // SH: vertical fu (rows 0..3) then horizontal fv
            const float h06 = tile[m][pr][pc] + tile[m][pr][pc + 6];
            const float h15 = tile[m][pr][pc + 1] + tile[m][pr][pc + 5];
            const float h24 = tile[m][pr][pc + 2] + tile[m][pr][pc + 4];
            const float accH = fmaf(fv0, h06, fmaf(fv1, h15, fmaf(fv2, h24, tile[m][pr][pc + 3])));
            // SV: vertical fv (rows 4..7) then horizontal fu
            const float g06 = tile[m][4 + pr][pc] + tile[m][4 + pr][pc + 6];
            const float g15 = tile[m][4 + pr][pc + 1] + tile[m][4 + pr][pc + 5];
            const float g24 = tile[m][4 + pr][pc + 2] + tile[m][4 + pr][pc + 4];
            const float accV = fmaf(fu0, g06, fmaf(fu1, g15, fmaf(fu2, g24, tile[m][4 + pr][pc + 3])));
            lowr[mm] = fmaf(aH, accH, aV * accV);
        }
    }
    __syncthreads();   // all B2 reads done before overlaying low onto vu region

    // ---- overlay: low[m][px] -> tf[m*380 + px] (floats 0..127 = dead vu rows) ----
    {
        const int m0 = mh * 8;
#pragma unroll
        for (int mm = 0; mm < 8; ++mm)
            tf[(m0 + mm) * MSTRIDE + px] = lowr[mm];   // lanes consecutive: conflict-free
    }
    __syncthreads();

    // ---- Phase C: expand; thread = (px-pair, 32-channel group within half) ----
    const int p2 = tid & 63;              // float2 pixel-pair index, 0..63
    const int c0 = __builtin_amdgcn_readfirstlane((chh << 7) + ((tid >> 6) << 5));

    const float2* low2 = (const float2*)tf;   // float2 view; mid stride 190
    float2 lw[MIDn];
#pragma unroll
    for (int m = 0; m < MIDn; ++m) lw[m] = low2[m * (MSTRIDE / 2) + p2];

    const int gh  = th0 + (p2 >> 4);
    const int gw2 = (tw0 >> 1) + (p2 & 15);
    float2* ob = out2 + ((size_t)b * Cn + c0) * (HWn / 2) + gh * (Wn / 2) + gw2;

#pragma unroll 4
    for (int ci = 0; ci < 32; ++ci) {
        const float* w = we + (size_t)(c0 + ci) * MIDn;   // lane-uniform -> s_load
        float2 o = make_float2(0.f, 0.f);
#pragma unroll
        for (int m = 0; m < MIDn; ++m) {
            o.x = fmaf(w[m], lw[m].x, o.x);
            o.y = fmaf(w[m], lw[m].y, o.y);
        }
        ob[(size_t)ci * (HWn / 2)] = o;   // 4 x 128 B segments / wave
    }
}

// ---------------------------------------------------------------------------
extern "C" void kernel_launch(void* const* d_in, const int* in_sizes, int n_in,
                              void* d_out, int out_size, void* d_ws, size_t ws_size,
                              hipStream_t stream) {
    const float* x   = (const float*)d_in[0];  // (8,256,128,128)
    const float* ang = (const float*)d_in[1];  // (8,128,128)
    const float* wr  = (const float*)d_in[2];  // (16,256)
    const float* we  = (const float*)d_in[3];  // (256,16)
    float*       out = (float*)d_out;          // (8,256,128,128)

    float* xlow = (float*)d_ws;                // 8 MiB: (8,16,128,128)

    reduce_k<<<dim3((HWn / 2) / 64, Bn), dim3(256), 0, stream>>>(
        (const float2*)x, wr, (float2*)xlow);
    conv_expand_k<<<dim3(128, 2, Bn), dim3(256), 0, stream>>>(
        xlow, ang, we, (float2*)out);
}

// Round 7
// 257.631 us; speedup vs baseline: 1.0433x; 1.0337x over previous
//
#include <hip/hip_runtime.h>

// Problem constants (fixed by setup_inputs).
#define Bn   8
#define Cn   256
#define MIDn 16
#define Hn   128
#define Wn   128
#define HWn  (Hn * Wn)      // 16384

// ---------------------------------------------------------------------------
// FINAL (revert to round-3 best, 257.9 us). Session ledger:
//   R1 fuse conv+expand (2 blk/CU)        : 314.7  (occupancy regression)
//   R2 4x parallelism (4 blk/CU)          : 258.8  (the win: waves/CU)
//   R3 separable factorization            : 257.9  (compute cut: null -> not VALU-bound)
//   R4 LDS slim, 6 blk/CU cap             : 259.4  (null: grid already fully resident)
//   R5 barrier-free tail, scalar stores   : 268.8  (negative: store-instr count doubled)
//   R6 channel-split x2 blocks/tile       : 266.3  (negative: duplicated stage cost)
// Remaining gap to the 48 us traffic floor is phase-latency residue that
// compute-cut / residency / de-sync / turnover all failed to compress,
// under ~188 us of fixed harness overhead (512 MiB re-poison fills).
// ---------------------------------------------------------------------------

// ---------------------------------------------------------------------------
// KA: full 1x1 reduce (256 -> 16), intra-block channel split.
// Block covers 64 float2 pixels (128 px); wave w handles channels [64w,64w+64).
// LDS combine (4 waves -> 1) then single xlow write.
// Grid (128, 8) = 1024 blocks = 4/CU; ~27 us vs 22.6 us traffic floor.
// ---------------------------------------------------------------------------
__global__ __launch_bounds__(256, 4) void reduce_k(const float2* __restrict__ x2,
                                                   const float* __restrict__ wr,
                                                   float2* __restrict__ xlow2) {
    __shared__ float2 comb[4][MIDn][64];    // 32768 B

    const int tid = threadIdx.x;
    const int p2  = tid & 63;               // float2 index within block's range
    const int wv  = tid >> 6;               // wave id = channel group
    const int b   = blockIdx.y;
    const int p0  = blockIdx.x * 64;

    // wave-uniform channel base -> SGPR, so weight reads become s_loads
    const int c0 = __builtin_amdgcn_readfirstlane(wv << 6);

    const float2* xb = x2 + ((size_t)b * Cn + c0) * (HWn / 2) + p0 + p2;

    float2 acc[MIDn];
#pragma unroll
    for (int m = 0; m < MIDn; ++m) acc[m] = make_float2(0.f, 0.f);

#pragma unroll 8
    for (int c = 0; c < 64; ++c) {
        const float2 v = xb[(size_t)c * (HWn / 2)];   // 512 B / wave, coalesced
        const float* w = wr + (c0 + c);               // lane-uniform -> s_load
#pragma unroll
        for (int m = 0; m < MIDn; ++m) {
            const float wm = w[m * Cn];
            acc[m].x = fmaf(v.x, wm, acc[m].x);
            acc[m].y = fmaf(v.y, wm, acc[m].y);
        }
    }

#pragma unroll
    for (int m = 0; m < MIDn; ++m) comb[wv][m][p2] = acc[m];
    __syncthreads();

    float2* ob = xlow2 + (size_t)b * MIDn * (HWn / 2) + p0;
#pragma unroll
    for (int k = 0; k < 4; ++k) {
        const int idx = k * 256 + tid;
        const int m   = idx >> 6;
        const int q   = idx & 63;
        const float2 s0 = comb[0][m][q];
        const float2 s1 = comb[1][m][q];
        const float2 s2 = comb[2][m][q];
        const float2 s3 = comb[3][m][q];
        float2 s;
        s.x = (s0.x + s1.x) + (s2.x + s3.x);
        s.y = (s0.y + s1.y) + (s2.y + s3.y);
        ob[(size_t)m * (HWn / 2) + q] = s;
    }
}

// ---------------------------------------------------------------------------
// KB: fused conv + expand with SEPARABLE factorization (round-3 structure).
//   combined(p) = aH(p)*(fu (x) fv) + aV(p)*(fv (x) fu)
//   => out_low[m,p] = aH(p)*SH[m,p] + aV(p)*SV[m,p],
//      SH/SV pixel-independent separable 7x7 convs of xlow.
// Phase A : stage [16][10][38] halo tile (24.3 KB).
// Phase B1: vertical 7-tap (fu AND fv) per column strip, in-place
//           (tile[m][0..3]=vu, tile[m][4..7]=vv).
// Phase B2: horizontal 7-tap + 2-FMA blend -> low[16][128] (2 threads/px).
// Phase C : expand, 4 wave-groups x 64 channels, float2 stores.
// Grid (128,8) = 1024 blocks = 4/CU (fully resident), LDS 32.5 KB.
// ---------------------------------------------------------------------------
#define TW 32
#define TH 4
#define HR (TH + 6)   // 10
#define WR (TW + 6)   // 38
#define NPX (TH * TW) // 128
#define NSTRIP (MIDn * WR)  // 608

__device__ __forceinline__ int reflect_i(int i, int n) {
    return i < 0 ? -i : (i >= n ? 2 * n - 2 - i : i);
}

__global__ __launch_bounds__(256, 4) void conv_expand_k(const float* __restrict__ xlow,
                                                        const float* __restrict__ ang,
                                                        const float* __restrict__ we,
                                                        float2* __restrict__ out2) {
    __shared__ float tile[MIDn][HR][WR];  // 24320 B
    __shared__ float low[MIDn][NPX];      //  8192 B

    const int tid = threadIdx.x;
    const int b   = blockIdx.y;
    const int rem = blockIdx.x;           // 0..127 -> 32 x 4 tiles
    const int th0 = (rem >> 2) * TH;
    const int tw0 = (rem & 3) * TW;

    // issue the angle load early (independent of LDS phases)
    const int px = tid & (NPX - 1);       // 0..127
    const int mh = tid >> 7;              // 0/1 -> mids [8*mh, 8*mh+8)
    const int pr = px >> 5;
    const int pc = px & 31;
    const float a = ang[(size_t)b * HWn + (th0 + pr) * Wn + (tw0 + pc)];

    // basis taps (fu3 = fv3 = 1 exactly)
    const float fu0 = 0.48675226f, fu1 = 0.72614904f, fu2 = 0.92311635f;
    const float fv0 = 0.011108997f, fv1 = 0.13533528f, fv2 = 0.60653066f;

    // ---- Phase A: stage halo tile (reflect-indexed) for all 16 mids ----
    const float* pb = xlow + (size_t)b * MIDn * HWn;
    for (int idx = tid; idx < MIDn * HR * WR; idx += 256) {
        const int m  = idx / (HR * WR);
        const int r2 = idx - m * (HR * WR);
        const int r  = r2 / WR;
        const int cc = r2 - r * WR;
        const int gr = reflect_i(th0 + r - 3, Hn);
        const int gc = reflect_i(tw0 + cc - 3, Wn);
        tile[m][r][cc] = pb[(size_t)m * HWn + gr * Wn + gc];
    }
    __syncthreads();

    // ---- Phase B1: vertical pass, in-place. 608 column strips / 256 thr. ----
    float oA[8], oB[8], oC[8];
    int mA, cA, mB, cB, mC, cC;
    bool hasC;
    {
        {   // strip A: s = tid
            const int s = tid;
            mA = s / WR; cA = s - mA * WR;
            float t[HR];
#pragma unroll
            for (int r = 0; r < HR; ++r) t[r] = tile[mA][r][cA];
#pragma unroll
            for (int r = 0; r < TH; ++r) {
                const float p06 = t[r] + t[r + 6];
                const float p15 = t[r + 1] + t[r + 5];
                const float p24 = t[r + 2] + t[r + 4];
                const float p3  = t[r + 3];
                oA[r]     = fmaf(fu0, p06, fmaf(fu1, p15, fmaf(fu2, p24, p3)));
                oA[4 + r] = fmaf(fv0, p06, fmaf(fv1, p15, fmaf(fv2, p24, p3)));
            }
        }
        {   // strip B: s = tid + 256
            const int s = tid + 256;
            mB = s / WR; cB = s - mB * WR;
            float t[HR];
#pragma unroll
            for (int r = 0; r < HR; ++r) t[r] = tile[mB][r][cB];
#pragma unroll
            for (int r = 0; r < TH; ++r) {
                const float p06 = t[r] + t[r + 6];
                const float p15 = t[r + 1] + t[r + 5];
                const float p24 = t[r + 2] + t[r + 4];
                const float p3  = t[r + 3];
                oB[r]     = fmaf(fu0, p06, fmaf(fu1, p15, fmaf(fu2, p24, p3)));
                oB[4 + r] = fmaf(fv0, p06, fmaf(fv1, p15, fmaf(fv2, p24, p3)));
            }
        }
        // strip C: s = tid + 512 (only tid < 96)
        hasC = (tid + 512) < NSTRIP;
        {
            const int s = hasC ? (tid + 512) : tid;   // safe dummy when !hasC
            mC = s / WR; cC = s - mC * WR;
            float t[HR];
#pragma unroll
            for (int r = 0; r < HR; ++r) t[r] = tile[mC][r][cC];
#pragma unroll
            for (int r = 0; r < TH; ++r) {
                const float p06 = t[r] + t[r + 6];
                const float p15 = t[r + 1] + t[r + 5];
                const float p24 = t[r + 2] + t[r + 4];
                const float p3  = t[r + 3];
                oC[r]     = fmaf(fu0, p06, fmaf(fu1, p15, fmaf(fu2, p24, p3)));
                oC[4 + r] = fmaf(fv0, p06, fmaf(fv1, p15, fmaf(fv2, p24, p3)));
            }
        }
    }
    __syncthreads();   // all reads of tile complete before in-place writes

#pragma unroll
    for (int r = 0; r < TH; ++r) {
        tile[mA][r][cA]     = oA[r];
        tile[mA][4 + r][cA] = oA[4 + r];
        tile[mB][r][cB]     = oB[r];
        tile[mB][4 + r][cB] = oB[4 + r];
    }
    if (hasC) {
#pragma unroll
        for (int r = 0; r < TH; ++r) {
            tile[mC][r][cC]     = oC[r];
            tile[mC][4 + r][cC] = oC[4 + r];
        }
    }
    __syncthreads();
    // now: tile[m][0..3][*] = vu (fu-vertical), tile[m][4..7][*] = vv (fv-vertical)

    // ---- Phase B2: horizontal 7-tap + blend; thread = (px, mid-half) ----
    {
        const float ch = cosf(a);
        const float wh = ch * ch;
        const float su = 1.f + 2.f * (0.48675226f + 0.72614904f + 0.92311635f);
        const float sv = 1.f + 2.f * (0.011108997f + 0.13533528f + 0.60653066f);
        const float inv = 1.f / (su * sv + 1e-8f);    // matches ker.sum()+1e-8
        const float aH = wh * inv;
        const float aV = (1.f - wh) * inv;

        const int m0 = mh * 8;
#pragma unroll
        for (int mm = 0; mm < 8; ++mm) {
            const int m = m0 + mm;
            // SH: vertical fu (rows 0..3) then horizontal fv
            const float h06 = tile[m][pr][pc] + tile[m][pr][pc + 6];
            const float h15 = tile[m][pr][pc + 1] + tile[m][pr][pc + 5];
            const float h24 = tile[m][pr][pc + 2] + tile[m][pr][pc + 4];
            const float accH = fmaf(fv0, h06, fmaf(fv1, h15, fmaf(fv2, h24, tile[m][pr][pc + 3])));
            // SV: vertical fv (rows 4..7) then horizontal fu
            const float g06 = tile[m][4 + pr][pc] + tile[m][4 + pr][pc + 6];
            const float g15 = tile[m][4 + pr][pc + 1] + tile[m][4 + pr][pc + 5];
            const float g24 = tile[m][4 + pr][pc + 2] + tile[m][4 + pr][pc + 4];
            const float accV = fmaf(fu0, g06, fmaf(fu1, g15, fmaf(fu2, g24, tile[m][4 + pr][pc + 3])));
            low[m][px] = fmaf(aH, accH, aV * accV);
        }
    }
    __syncthreads();

    // ---- Phase C: expand; thread = (px-pair, channel-group of 64) ----
    const int p2 = tid & 63;              // float2 pixel-pair index, 0..63
    const int c0 = __builtin_amdgcn_readfirstlane((tid >> 6) << 6);  // wave-uniform

    const float2* low2 = (const float2*)low;  // [16][64]
    float2 lw[MIDn];
#pragma unroll
    for (int m = 0; m < MIDn; ++m) lw[m] = low2[m * 64 + p2];   // ds_read_b64

    const int gh  = th0 + (p2 >> 4);
    const int gw2 = (tw0 >> 1) + (p2 & 15);
    float2* ob = out2 + ((size_t)b * Cn + c0) * (HWn / 2) + gh * (Wn / 2) + gw2;

#pragma unroll 4
    for (int ci = 0; ci < 64; ++ci) {
        const float* w = we + (size_t)(c0 + ci) * MIDn;   // lane-uniform -> s_load
        float2 o = make_float2(0.f, 0.f);
#pragma unroll
        for (int m = 0; m < MIDn; ++m) {
            o.x = fmaf(w[m], lw[m].x, o.x);
            o.y = fmaf(w[m], lw[m].y, o.y);
        }
        ob[(size_t)ci * (HWn / 2)] = o;   // 4 x 128 B segments / wave
    }
}

// ---------------------------------------------------------------------------
extern "C" void kernel_launch(void* const* d_in, const int* in_sizes, int n_in,
                              void* d_out, int out_size, void* d_ws, size_t ws_size,
                              hipStream_t stream) {
    const float* x   = (const float*)d_in[0];  // (8,256,128,128)
    const float* ang = (const float*)d_in[1];  // (8,128,128)
    const float* wr  = (const float*)d_in[2];  // (16,256)
    const float* we  = (const float*)d_in[3];  // (256,16)
    float*       out = (float*)d_out;          // (8,256,128,128)

    float* xlow = (float*)d_ws;                // 8 MiB: (8,16,128,128)

    reduce_k<<<dim3((HWn / 2) / 64, Bn), dim3(256), 0, stream>>>(
        (const float2*)x, wr, (float2*)xlow);
    conv_expand_k<<<dim3(128, Bn), dim3(256), 0, stream>>>(xlow, ang, we, (float2*)out);
}